// Round 1
// baseline (2107.534 us; speedup 1.0000x reference)
//
#include <hip/hip_runtime.h>
#include <hip/hip_bf16.h>
#include <math.h>

#define B_ 8
#define C_ 256
#define H_ 64
#define W_ 64
#define N_ 4096
#define M_ 1024
#define HW_ 4096

// ---------------------------------------------------------------------------
// conv 3x3, stride 1, pad 1 (q path). Implicit GEMM: [co=256] x [px=8*4096], K=2304.
// Tile: 128 co x 128 px (2 image rows), 8x8 micro per thread, 256 threads.
__global__ __launch_bounds__(256) void conv3x3_kernel(
    const float* __restrict__ x, const float* __restrict__ Wq,
    const float* __restrict__ bq, float* __restrict__ out)
{
    const int K = 2304;
    int blk = blockIdx.x;
    int cot = blk & 1;          // 2 co tiles
    int ht  = (blk >> 1) & 31;  // 32 row-pair tiles
    int b   = blk >> 6;         // 8 batches
    int t = threadIdx.x;
    int tx = t & 15, ty = t >> 4;
    __shared__ float As[16][132];   // [k][co], pad 132 (mult of 4: b128-aligned, 2-way banks)
    __shared__ float Bs[16][132];   // [k][px]
    float acc[8][8] = {};
    const int co0 = cot * 128;
    const float* Wbase = Wq + (size_t)co0 * K;
    const float* xb = x + (size_t)b * C_ * HW_;
    const int h0 = ht * 2;
    const int a_kk  = t & 15,  a_colb = t >> 4;
    const int b_px  = t & 127, b_kkb  = t >> 7;

    for (int k0 = 0; k0 < K; k0 += 16) {
        // stage A: W[co][k] -> As[k][co]; consecutive lanes read consecutive k
        #pragma unroll
        for (int r = 0; r < 8; ++r) {
            int col = r * 16 + a_colb;
            As[a_kk][col] = Wbase[(size_t)col * K + (k0 + a_kk)];
        }
        // stage B: im2col on the fly; consecutive lanes -> consecutive px (coalesced)
        #pragma unroll
        for (int r = 0; r < 8; ++r) {
            int kk = 2 * r + b_kkb;
            int kg = k0 + kk;
            int ci = kg / 9;
            int tap = kg - ci * 9;
            int kh = tap / 3;
            int kw = tap - kh * 3;
            int hh = h0 + (b_px >> 6) + kh - 1;
            int ww = (b_px & 63) + kw - 1;
            float v = 0.f;
            if (((unsigned)hh < 64u) && ((unsigned)ww < 64u))
                v = xb[(size_t)ci * HW_ + hh * 64 + ww];
            Bs[kk][b_px] = v;
        }
        __syncthreads();
        #pragma unroll
        for (int kk = 0; kk < 16; ++kk) {
            float a[8], bb[8];
            *(float4*)&a[0]  = *(const float4*)&As[kk][ty * 8];
            *(float4*)&a[4]  = *(const float4*)&As[kk][ty * 8 + 4];
            *(float4*)&bb[0] = *(const float4*)&Bs[kk][tx * 8];
            *(float4*)&bb[4] = *(const float4*)&Bs[kk][tx * 8 + 4];
            #pragma unroll
            for (int i = 0; i < 8; ++i)
                #pragma unroll
                for (int j = 0; j < 8; ++j)
                    acc[i][j] = fmaf(a[i], bb[j], acc[i][j]);
        }
        __syncthreads();
    }
    // epilogue: add conv bias (needed: GN mean does NOT cancel per-channel bias)
    #pragma unroll
    for (int i = 0; i < 8; ++i) {
        int co = co0 + ty * 8 + i;
        float bv = bq[co];
        float* op = out + ((size_t)(b * C_ + co)) * HW_ + ht * 128 + tx * 8;
        float4 o0 = make_float4(acc[i][0] + bv, acc[i][1] + bv, acc[i][2] + bv, acc[i][3] + bv);
        float4 o1 = make_float4(acc[i][4] + bv, acc[i][5] + bv, acc[i][6] + bv, acc[i][7] + bv);
        *(float4*)op = o0;
        *(float4*)(op + 4) = o1;
    }
}

// ---------------------------------------------------------------------------
// conv 2x2, stride 2, pad 0 (k and v paths fused). Non-overlapping patches ->
// pure GEMM: [co] x [m=1024], K = 256*4 = 1024. Tile 128x128, 8x8 micro.
__global__ __launch_bounds__(256) void conv2x2_kernel(
    const float* __restrict__ y,
    const float* __restrict__ Wk, const float* __restrict__ bk,
    const float* __restrict__ Wv, const float* __restrict__ bv,
    float* __restrict__ kout, float* __restrict__ vout)
{
    const int K = 1024;
    int blk = blockIdx.x;
    int cot = blk & 3;          // 4 co' tiles over (k:256 | v:256)
    int mt  = (blk >> 2) & 7;   // 8 m tiles
    int b   = blk >> 5;         // 8 batches
    int t = threadIdx.x;
    int tx = t & 15, ty = t >> 4;
    const float* Wt; const float* bt; float* dst; int co0;
    if (cot < 2) { Wt = Wk; bt = bk; dst = kout; co0 = cot * 128; }
    else         { Wt = Wv; bt = bv; dst = vout; co0 = (cot - 2) * 128; }
    __shared__ float As[16][132];
    __shared__ float Bs[16][132];
    float acc[8][8] = {};
    const float* Wbase = Wt + (size_t)co0 * K;
    const float* yb = y + (size_t)b * C_ * HW_;
    const int m0 = mt * 128;
    const int a_kk = t & 15,  a_colb = t >> 4;
    const int b_px = t & 127, b_kkb  = t >> 7;

    for (int k0 = 0; k0 < K; k0 += 16) {
        #pragma unroll
        for (int r = 0; r < 8; ++r) {
            int col = r * 16 + a_colb;
            As[a_kk][col] = Wbase[(size_t)col * K + (k0 + a_kk)];
        }
        #pragma unroll
        for (int r = 0; r < 8; ++r) {
            int kk = 2 * r + b_kkb;
            int kg = k0 + kk;
            int ci = kg >> 2;
            int tap = kg & 3;
            int kh = tap >> 1;
            int kw = tap & 1;
            int m = m0 + b_px;
            int mh = m >> 5, mw = m & 31;
            Bs[kk][b_px] = yb[(size_t)ci * HW_ + (2 * mh + kh) * 64 + 2 * mw + kw];
        }
        __syncthreads();
        #pragma unroll
        for (int kk = 0; kk < 16; ++kk) {
            float a[8], bb[8];
            *(float4*)&a[0]  = *(const float4*)&As[kk][ty * 8];
            *(float4*)&a[4]  = *(const float4*)&As[kk][ty * 8 + 4];
            *(float4*)&bb[0] = *(const float4*)&Bs[kk][tx * 8];
            *(float4*)&bb[4] = *(const float4*)&Bs[kk][tx * 8 + 4];
            #pragma unroll
            for (int i = 0; i < 8; ++i)
                #pragma unroll
                for (int j = 0; j < 8; ++j)
                    acc[i][j] = fmaf(a[i], bb[j], acc[i][j]);
        }
        __syncthreads();
    }
    #pragma unroll
    for (int i = 0; i < 8; ++i) {
        int co = co0 + ty * 8 + i;
        float bv = bt[co];
        float* op = dst + ((size_t)(b * C_ + co)) * M_ + m0 + tx * 8;
        float4 o0 = make_float4(acc[i][0] + bv, acc[i][1] + bv, acc[i][2] + bv, acc[i][3] + bv);
        float4 o1 = make_float4(acc[i][4] + bv, acc[i][5] + bv, acc[i][6] + bv, acc[i][7] + bv);
        *(float4*)op = o0;
        *(float4*)(op + 4) = o1;
    }
}

// ---------------------------------------------------------------------------
// GroupNorm stats: one block per (batch, group); reduce 8*S elements.
__global__ __launch_bounds__(256) void gn_stats_kernel(
    const float* __restrict__ buf, float* __restrict__ stats, int S)
{
    int bg = blockIdx.x;  // b*32 + g
    const float4* p = (const float4*)(buf + (size_t)bg * 8 * S);
    int n4 = 2 * S;
    float s = 0.f, s2 = 0.f;
    for (int i = threadIdx.x; i < n4; i += 256) {
        float4 vv = p[i];
        s  += vv.x + vv.y + vv.z + vv.w;
        s2 += vv.x * vv.x + vv.y * vv.y + vv.z * vv.z + vv.w * vv.w;
    }
    for (int d = 1; d < 64; d <<= 1) { s += __shfl_xor(s, d); s2 += __shfl_xor(s2, d); }
    __shared__ float red[8];
    int w = threadIdx.x >> 6;
    if ((threadIdx.x & 63) == 0) { red[w] = s; red[w + 4] = s2; }
    __syncthreads();
    if (threadIdx.x == 0) {
        s  = red[0] + red[1] + red[2] + red[3];
        s2 = red[4] + red[5] + red[6] + red[7];
        float invn = 1.f / (float)(8 * S);
        float mean = s * invn;
        float var = s2 * invn - mean * mean;
        if (var < 0.f) var = 0.f;
        stats[bg * 2]     = mean;
        stats[bg * 2 + 1] = 1.f / sqrtf(var + 1e-5f);
    }
}

// GroupNorm apply + affine + SiLU, in place, float4-vectorized.
__global__ __launch_bounds__(256) void gn_silu_kernel(
    float* __restrict__ buf, const float* __restrict__ stats,
    const float* __restrict__ scale, const float* __restrict__ bias,
    int sshift, int total4)
{
    int idx = blockIdx.x * 256 + threadIdx.x;
    if (idx >= total4) return;
    size_t e = (size_t)idx * 4;
    int c  = (int)((e >> sshift) & 255);
    int gg = (int)(e >> (sshift + 3));   // b*32 + g
    float mean = stats[gg * 2], rstd = stats[gg * 2 + 1];
    float a  = scale[c] * rstd;
    float bb = bias[c] - mean * a;
    float4 vv = ((float4*)buf)[idx];
    float y0 = vv.x * a + bb;
    float y1 = vv.y * a + bb;
    float y2 = vv.z * a + bb;
    float y3 = vv.w * a + bb;
    vv.x = y0 / (1.f + __expf(-y0));
    vv.y = y1 / (1.f + __expf(-y1));
    vv.z = y2 / (1.f + __expf(-y2));
    vv.w = y3 / (1.f + __expf(-y3));
    ((float4*)buf)[idx] = vv;
}

// ---------------------------------------------------------------------------
// Fused attention. Per block: one batch, TN=8 queries. Scores [8][1024] in LDS.
// blockIdx % 8 == batch -> round-robin XCD assignment pins each batch's 2MB k+v
// into one XCD's 4MB L2.
#define TN 8
__global__ __launch_bounds__(256) void attn_kernel(
    const float* __restrict__ q, const float* __restrict__ k,
    const float* __restrict__ v, const float* __restrict__ gamma,
    float* __restrict__ out)
{
    __shared__ float sc[TN][1024];   // 32 KB
    __shared__ float aux[64 * 68];   // 17 KB: q-tile in phase1, v-stage in phase2
    int blk = blockIdx.x;
    int bat = blk & 7;
    int nt  = blk >> 3;    // 0..511
    int n0  = nt * TN;
    int t = threadIdx.x;

    // load q tile -> aux[ci*8 + nl]
    const float* qb = q + (size_t)bat * C_ * N_ + n0;
    #pragma unroll
    for (int r = 0; r < TN; ++r) {
        int e = r * 256 + t;     // 0..2047
        int ci = e >> 3;
        int nl = e & 7;
        aux[e] = qb[(size_t)ci * N_ + nl];
    }
    __syncthreads();

    // phase 1: S = q^T k * (1/16). Thread owns m in {t, t+256, t+512, t+768}.
    const float* kb = k + (size_t)bat * C_ * M_;
    float acc[TN][4] = {};
    for (int ci = 0; ci < 256; ++ci) {
        float kv0 = kb[ci * M_ + t];
        float kv1 = kb[ci * M_ + t + 256];
        float kv2 = kb[ci * M_ + t + 512];
        float kv3 = kb[ci * M_ + t + 768];
        float qv[TN];
        *(float4*)&qv[0] = *(const float4*)&aux[ci * TN];
        *(float4*)&qv[4] = *(const float4*)&aux[ci * TN + 4];
        #pragma unroll
        for (int nq = 0; nq < TN; ++nq) {
            acc[nq][0] = fmaf(qv[nq], kv0, acc[nq][0]);
            acc[nq][1] = fmaf(qv[nq], kv1, acc[nq][1]);
            acc[nq][2] = fmaf(qv[nq], kv2, acc[nq][2]);
            acc[nq][3] = fmaf(qv[nq], kv3, acc[nq][3]);
        }
    }
    #pragma unroll
    for (int nq = 0; nq < TN; ++nq) {
        sc[nq][t]       = acc[nq][0] * 0.0625f;
        sc[nq][t + 256] = acc[nq][1] * 0.0625f;
        sc[nq][t + 512] = acc[nq][2] * 0.0625f;
        sc[nq][t + 768] = acc[nq][3] * 0.0625f;
    }
    __syncthreads();

    // softmax over 1024 keys; 32 lanes per row (rows live within one wave half)
    {
        int r = t >> 5, l = t & 31;
        float mx = -1e30f;
        #pragma unroll
        for (int j = 0; j < 32; ++j) mx = fmaxf(mx, sc[r][l + j * 32]);
        for (int d = 1; d < 32; d <<= 1) mx = fmaxf(mx, __shfl_xor(mx, d));
        float sum = 0.f;
        #pragma unroll
        for (int j = 0; j < 32; ++j) {
            float e = __expf(sc[r][l + j * 32] - mx);
            sc[r][l + j * 32] = e;
            sum += e;
        }
        for (int d = 1; d < 32; d <<= 1) sum += __shfl_xor(sum, d);
        float rinv = 1.f / sum;
        #pragma unroll
        for (int j = 0; j < 32; ++j) sc[r][l + j * 32] *= rinv;
    }
    __syncthreads();

    // phase 2: out[co][n] = sum_m v[co][m] * P[n][m], co-tiles of 64.
    // thread: tg = co-group (4 co), ms = m-subset (in-wave), qg = wave -> 2 rows.
    const float* vb = v + (size_t)bat * C_ * M_;
    float g = gamma[0];
    int tg = t & 15;
    int ms = (t >> 4) & 3;
    int qg = t >> 6;
    float* vs = aux;
    for (int ct = 0; ct < 4; ++ct) {
        int co0 = ct * 64;
        float pa[2][4] = {};
        for (int mt2 = 0; mt2 < 16; ++mt2) {
            int m0 = mt2 * 64;
            __syncthreads();   // previous readers done before restaging
            #pragma unroll
            for (int rr = 0; rr < 16; ++rr) {
                int e = rr * 256 + t;
                int col = e >> 6;      // co_l 0..63
                int ml  = e & 63;
                vs[ml * 68 + col] = vb[(size_t)(co0 + col) * M_ + m0 + ml];
            }
            __syncthreads();
            #pragma unroll
            for (int i = 0; i < 16; ++i) {
                int ml = ms * 16 + i;
                float vv[4];
                *(float4*)&vv[0] = *(const float4*)&vs[ml * 68 + tg * 4];
                float p0 = sc[qg * 2 + 0][m0 + ml];
                float p1 = sc[qg * 2 + 1][m0 + ml];
                #pragma unroll
                for (int jc = 0; jc < 4; ++jc) {
                    pa[0][jc] = fmaf(p0, vv[jc], pa[0][jc]);
                    pa[1][jc] = fmaf(p1, vv[jc], pa[1][jc]);
                }
            }
        }
        // reduce partial sums over the 4 m-subsets (lanes xor 16, 32 within wave)
        #pragma unroll
        for (int jq = 0; jq < 2; ++jq)
            #pragma unroll
            for (int jc = 0; jc < 4; ++jc) {
                float s = pa[jq][jc];
                s += __shfl_xor(s, 16);
                s += __shfl_xor(s, 32);
                pa[jq][jc] = s;
            }
        if (ms == 0) {
            #pragma unroll
            for (int jc = 0; jc < 4; ++jc) {
                int co = co0 + tg * 4 + jc;
                float2 o = make_float2(g * pa[0][jc], g * pa[1][jc]);
                *(float2*)(out + ((size_t)(bat * C_ + co)) * N_ + n0 + qg * 2) = o;
            }
        }
    }
}

// ---------------------------------------------------------------------------
extern "C" void kernel_launch(void* const* d_in, const int* in_sizes, int n_in,
                              void* d_out, int out_size, void* d_ws, size_t ws_size,
                              hipStream_t stream)
{
    const float* x   = (const float*)d_in[0];
    const float* y   = (const float*)d_in[1];
    const float* Wq  = (const float*)d_in[2];
    const float* bq  = (const float*)d_in[3];
    const float* gqs = (const float*)d_in[4];
    const float* gqb = (const float*)d_in[5];
    const float* Wk  = (const float*)d_in[6];
    const float* bk  = (const float*)d_in[7];
    const float* gks = (const float*)d_in[8];
    const float* gkb = (const float*)d_in[9];
    const float* Wv  = (const float*)d_in[10];
    const float* bv  = (const float*)d_in[11];
    const float* gvs = (const float*)d_in[12];
    const float* gvb = (const float*)d_in[13];
    const float* gamma = (const float*)d_in[14];
    float* out = (float*)d_out;

    // workspace layout (floats): q 8.39M | k 2.10M | v 2.10M | stats 3*512  (~50.3 MB)
    float* ws  = (float*)d_ws;
    float* qb  = ws;
    float* kb  = qb + 8388608;
    float* vb  = kb + 2097152;
    float* stq = vb + 2097152;
    float* stk = stq + 512;
    float* stv = stk + 512;

    conv3x3_kernel<<<512, 256, 0, stream>>>(x, Wq, bq, qb);
    conv2x2_kernel<<<256, 256, 0, stream>>>(y, Wk, bk, Wv, bv, kb, vb);
    gn_stats_kernel<<<256, 256, 0, stream>>>(qb, stq, 4096);
    gn_stats_kernel<<<256, 256, 0, stream>>>(kb, stk, 1024);
    gn_stats_kernel<<<256, 256, 0, stream>>>(vb, stv, 1024);
    gn_silu_kernel<<<8192, 256, 0, stream>>>(qb, stq, gqs, gqb, 12, 2097152);
    gn_silu_kernel<<<2048, 256, 0, stream>>>(kb, stk, gks, gkb, 10, 524288);
    gn_silu_kernel<<<2048, 256, 0, stream>>>(vb, stv, gvs, gvb, 10, 524288);
    attn_kernel<<<4096, 256, 0, stream>>>(qb, kb, vb, gamma, out);
}

// Round 2
// 1955.970 us; speedup vs baseline: 1.0775x; 1.0775x over previous
//
#include <hip/hip_runtime.h>
#include <hip/hip_bf16.h>
#include <math.h>

#define B_ 8
#define C_ 256
#define H_ 64
#define W_ 64
#define N_ 4096
#define M_ 1024
#define HW_ 4096

typedef __attribute__((ext_vector_type(8))) short short8;
typedef __attribute__((ext_vector_type(4))) float f32x4;

__device__ __forceinline__ unsigned short f2bf(float x) {
    unsigned u = __float_as_uint(x);
    u += 0x7fffu + ((u >> 16) & 1u);          // round-to-nearest-even
    return (unsigned short)(u >> 16);
}
__device__ __forceinline__ float bf2f(unsigned short h) {
    return __uint_as_float(((unsigned)h) << 16);
}

// ---------------------------------------------------------------------------
// conv 3x3, stride 1, pad 1 (q path). Implicit GEMM, 128co x 128px tile.
// Epilogue: +bias, split to bf16 hi/lo pair arrays (for later MFMA use).
__global__ __launch_bounds__(256) void conv3x3_kernel(
    const float* __restrict__ x, const float* __restrict__ Wq,
    const float* __restrict__ bq,
    unsigned short* __restrict__ qH, unsigned short* __restrict__ qL)
{
    const int K = 2304;
    int blk = blockIdx.x;
    int cot = blk & 1;
    int ht  = (blk >> 1) & 31;
    int b   = blk >> 6;
    int t = threadIdx.x;
    int tx = t & 15, ty = t >> 4;
    __shared__ float As[16][132];
    __shared__ float Bs[16][132];
    float acc[8][8] = {};
    const int co0 = cot * 128;
    const float* Wbase = Wq + (size_t)co0 * K;
    const float* xb = x + (size_t)b * C_ * HW_;
    const int h0 = ht * 2;
    const int a_kk  = t & 15,  a_colb = t >> 4;
    const int b_px  = t & 127, b_kkb  = t >> 7;

    for (int k0 = 0; k0 < K; k0 += 16) {
        #pragma unroll
        for (int r = 0; r < 8; ++r) {
            int col = r * 16 + a_colb;
            As[a_kk][col] = Wbase[(size_t)col * K + (k0 + a_kk)];
        }
        #pragma unroll
        for (int r = 0; r < 8; ++r) {
            int kk = 2 * r + b_kkb;
            int kg = k0 + kk;
            int ci = kg / 9;
            int tap = kg - ci * 9;
            int kh = tap / 3;
            int kw = tap - kh * 3;
            int hh = h0 + (b_px >> 6) + kh - 1;
            int ww = (b_px & 63) + kw - 1;
            float v = 0.f;
            if (((unsigned)hh < 64u) && ((unsigned)ww < 64u))
                v = xb[(size_t)ci * HW_ + hh * 64 + ww];
            Bs[kk][b_px] = v;
        }
        __syncthreads();
        #pragma unroll
        for (int kk = 0; kk < 16; ++kk) {
            float a[8], bb[8];
            *(float4*)&a[0]  = *(const float4*)&As[kk][ty * 8];
            *(float4*)&a[4]  = *(const float4*)&As[kk][ty * 8 + 4];
            *(float4*)&bb[0] = *(const float4*)&Bs[kk][tx * 8];
            *(float4*)&bb[4] = *(const float4*)&Bs[kk][tx * 8 + 4];
            #pragma unroll
            for (int i = 0; i < 8; ++i)
                #pragma unroll
                for (int j = 0; j < 8; ++j)
                    acc[i][j] = fmaf(a[i], bb[j], acc[i][j]);
        }
        __syncthreads();
    }
    #pragma unroll
    for (int i = 0; i < 8; ++i) {
        int co = co0 + ty * 8 + i;
        float bv = bq[co];
        size_t base = ((size_t)(b * C_ + co)) * HW_ + ht * 128 + tx * 8;
        unsigned hp[4], lp[4];
        #pragma unroll
        for (int j2 = 0; j2 < 4; ++j2) {
            float v0 = acc[i][2 * j2] + bv;
            float v1 = acc[i][2 * j2 + 1] + bv;
            unsigned short h0 = f2bf(v0), l0 = f2bf(v0 - bf2f(h0));
            unsigned short h1 = f2bf(v1), l1 = f2bf(v1 - bf2f(h1));
            hp[j2] = h0 | ((unsigned)h1 << 16);
            lp[j2] = l0 | ((unsigned)l1 << 16);
        }
        *(uint4*)(qH + base) = make_uint4(hp[0], hp[1], hp[2], hp[3]);
        *(uint4*)(qL + base) = make_uint4(lp[0], lp[1], lp[2], lp[3]);
    }
}

// ---------------------------------------------------------------------------
// conv 2x2, stride 2, pad 0 (k and v fused): pure GEMM, fp32 out (pre-GN).
__global__ __launch_bounds__(256) void conv2x2_kernel(
    const float* __restrict__ y,
    const float* __restrict__ Wk, const float* __restrict__ bk,
    const float* __restrict__ Wv, const float* __restrict__ bv,
    float* __restrict__ kout, float* __restrict__ vout)
{
    const int K = 1024;
    int blk = blockIdx.x;
    int cot = blk & 3;
    int mt  = (blk >> 2) & 7;
    int b   = blk >> 5;
    int t = threadIdx.x;
    int tx = t & 15, ty = t >> 4;
    const float* Wt; const float* bt; float* dst; int co0;
    if (cot < 2) { Wt = Wk; bt = bk; dst = kout; co0 = cot * 128; }
    else         { Wt = Wv; bt = bv; dst = vout; co0 = (cot - 2) * 128; }
    __shared__ float As[16][132];
    __shared__ float Bs[16][132];
    float acc[8][8] = {};
    const float* Wbase = Wt + (size_t)co0 * K;
    const float* yb = y + (size_t)b * C_ * HW_;
    const int m0 = mt * 128;
    const int a_kk = t & 15,  a_colb = t >> 4;
    const int b_px = t & 127, b_kkb  = t >> 7;

    for (int k0 = 0; k0 < K; k0 += 16) {
        #pragma unroll
        for (int r = 0; r < 8; ++r) {
            int col = r * 16 + a_colb;
            As[a_kk][col] = Wbase[(size_t)col * K + (k0 + a_kk)];
        }
        #pragma unroll
        for (int r = 0; r < 8; ++r) {
            int kk = 2 * r + b_kkb;
            int kg = k0 + kk;
            int ci = kg >> 2;
            int tap = kg & 3;
            int kh = tap >> 1;
            int kw = tap & 1;
            int m = m0 + b_px;
            int mh = m >> 5, mw = m & 31;
            Bs[kk][b_px] = yb[(size_t)ci * HW_ + (2 * mh + kh) * 64 + 2 * mw + kw];
        }
        __syncthreads();
        #pragma unroll
        for (int kk = 0; kk < 16; ++kk) {
            float a[8], bb[8];
            *(float4*)&a[0]  = *(const float4*)&As[kk][ty * 8];
            *(float4*)&a[4]  = *(const float4*)&As[kk][ty * 8 + 4];
            *(float4*)&bb[0] = *(const float4*)&Bs[kk][tx * 8];
            *(float4*)&bb[4] = *(const float4*)&Bs[kk][tx * 8 + 4];
            #pragma unroll
            for (int i = 0; i < 8; ++i)
                #pragma unroll
                for (int j = 0; j < 8; ++j)
                    acc[i][j] = fmaf(a[i], bb[j], acc[i][j]);
        }
        __syncthreads();
    }
    #pragma unroll
    for (int i = 0; i < 8; ++i) {
        int co = co0 + ty * 8 + i;
        float bv2 = bt[co];
        float* op = dst + ((size_t)(b * C_ + co)) * M_ + m0 + tx * 8;
        float4 o0 = make_float4(acc[i][0] + bv2, acc[i][1] + bv2, acc[i][2] + bv2, acc[i][3] + bv2);
        float4 o1 = make_float4(acc[i][4] + bv2, acc[i][5] + bv2, acc[i][6] + bv2, acc[i][7] + bv2);
        *(float4*)op = o0;
        *(float4*)(op + 4) = o1;
    }
}

// ---------------------------------------------------------------------------
// GroupNorm stats (fp32 input): one block per (batch, group).
__global__ __launch_bounds__(256) void gn_stats_kernel(
    const float* __restrict__ buf, float* __restrict__ stats, int S)
{
    int bg = blockIdx.x;
    const float4* p = (const float4*)(buf + (size_t)bg * 8 * S);
    int n4 = 2 * S;
    float s = 0.f, s2 = 0.f;
    for (int i = threadIdx.x; i < n4; i += 256) {
        float4 vv = p[i];
        s  += vv.x + vv.y + vv.z + vv.w;
        s2 += vv.x * vv.x + vv.y * vv.y + vv.z * vv.z + vv.w * vv.w;
    }
    for (int d = 1; d < 64; d <<= 1) { s += __shfl_xor(s, d); s2 += __shfl_xor(s2, d); }
    __shared__ float red[8];
    int w = threadIdx.x >> 6;
    if ((threadIdx.x & 63) == 0) { red[w] = s; red[w + 4] = s2; }
    __syncthreads();
    if (threadIdx.x == 0) {
        s  = red[0] + red[1] + red[2] + red[3];
        s2 = red[4] + red[5] + red[6] + red[7];
        float invn = 1.f / (float)(8 * S);
        float mean = s * invn;
        float var = s2 * invn - mean * mean;
        if (var < 0.f) var = 0.f;
        stats[bg * 2]     = mean;
        stats[bg * 2 + 1] = 1.f / sqrtf(var + 1e-5f);
    }
}

// GroupNorm stats from bf16 hi/lo pair (q path).
__global__ __launch_bounds__(256) void gn_stats_pair(
    const unsigned short* __restrict__ hi, const unsigned short* __restrict__ lo,
    float* __restrict__ stats, int S)
{
    int bg = blockIdx.x;
    const uint4* ph = (const uint4*)(hi + (size_t)bg * 8 * S);
    const uint4* pl = (const uint4*)(lo + (size_t)bg * 8 * S);
    int n8 = S;
    float s = 0.f, s2 = 0.f;
    for (int i = threadIdx.x; i < n8; i += 256) {
        uint4 a = ph[i], b2 = pl[i];
        unsigned ua[4] = {a.x, a.y, a.z, a.w}, ub[4] = {b2.x, b2.y, b2.z, b2.w};
        #pragma unroll
        for (int j = 0; j < 4; ++j) {
            float x0 = __uint_as_float(ua[j] << 16) + __uint_as_float(ub[j] << 16);
            float x1 = __uint_as_float(ua[j] & 0xffff0000u) + __uint_as_float(ub[j] & 0xffff0000u);
            s += x0 + x1;
            s2 += x0 * x0 + x1 * x1;
        }
    }
    for (int d = 1; d < 64; d <<= 1) { s += __shfl_xor(s, d); s2 += __shfl_xor(s2, d); }
    __shared__ float red[8];
    int w = threadIdx.x >> 6;
    if ((threadIdx.x & 63) == 0) { red[w] = s; red[w + 4] = s2; }
    __syncthreads();
    if (threadIdx.x == 0) {
        s  = red[0] + red[1] + red[2] + red[3];
        s2 = red[4] + red[5] + red[6] + red[7];
        float invn = 1.f / (float)(8 * S);
        float mean = s * invn;
        float var = s2 * invn - mean * mean;
        if (var < 0.f) var = 0.f;
        stats[bg * 2]     = mean;
        stats[bg * 2 + 1] = 1.f / sqrtf(var + 1e-5f);
    }
}

// GN + affine + SiLU (+extra scale) on bf16 pair, in place (q path, N=4096).
__global__ __launch_bounds__(256) void gn_silu_pair(
    unsigned short* __restrict__ hi, unsigned short* __restrict__ lo,
    const float* __restrict__ stats, const float* __restrict__ scale,
    const float* __restrict__ bias, float extra, int total8)
{
    int idx = blockIdx.x * 256 + threadIdx.x;
    if (idx >= total8) return;
    size_t e = (size_t)idx * 8;
    int c  = (int)((e >> 12) & 255);
    int gg = (int)(e >> 15);
    float mean = stats[gg * 2], rstd = stats[gg * 2 + 1];
    float a  = scale[c] * rstd;
    float bb = bias[c] - mean * a;
    uint4 uh = ((uint4*)hi)[idx], ul = ((uint4*)lo)[idx];
    unsigned ha[4] = {uh.x, uh.y, uh.z, uh.w}, la[4] = {ul.x, ul.y, ul.z, ul.w};
    unsigned oh[4], ol[4];
    #pragma unroll
    for (int j = 0; j < 4; ++j) {
        float x0 = __uint_as_float(ha[j] << 16) + __uint_as_float(la[j] << 16);
        float x1 = __uint_as_float(ha[j] & 0xffff0000u) + __uint_as_float(la[j] & 0xffff0000u);
        float y0 = x0 * a + bb, y1 = x1 * a + bb;
        float s0 = extra * y0 / (1.f + __expf(-y0));
        float s1 = extra * y1 / (1.f + __expf(-y1));
        unsigned short h0 = f2bf(s0), l0 = f2bf(s0 - bf2f(h0));
        unsigned short h1 = f2bf(s1), l1 = f2bf(s1 - bf2f(h1));
        oh[j] = h0 | ((unsigned)h1 << 16);
        ol[j] = l0 | ((unsigned)l1 << 16);
    }
    ((uint4*)hi)[idx] = make_uint4(oh[0], oh[1], oh[2], oh[3]);
    ((uint4*)lo)[idx] = make_uint4(ol[0], ol[1], ol[2], ol[3]);
}

// GN + affine + SiLU on fp32 v -> bf16 hi/lo pair, natural [C][M] layout.
__global__ __launch_bounds__(256) void gn_silu_split_v(
    const float* __restrict__ vf, unsigned short* __restrict__ hi,
    unsigned short* __restrict__ lo, const float* __restrict__ stats,
    const float* __restrict__ scale, const float* __restrict__ bias, int total8)
{
    int idx = blockIdx.x * 256 + threadIdx.x;
    if (idx >= total8) return;
    size_t e = (size_t)idx * 8;
    int c  = (int)((e >> 10) & 255);
    int gg = (int)(e >> 13);
    float mean = stats[gg * 2], rstd = stats[gg * 2 + 1];
    float a  = scale[c] * rstd;
    float bb = bias[c] - mean * a;
    float4 f0 = ((const float4*)vf)[idx * 2];
    float4 f1 = ((const float4*)vf)[idx * 2 + 1];
    float xs[8] = {f0.x, f0.y, f0.z, f0.w, f1.x, f1.y, f1.z, f1.w};
    unsigned oh[4], ol[4];
    #pragma unroll
    for (int j = 0; j < 4; ++j) {
        float y0 = xs[2 * j] * a + bb, y1 = xs[2 * j + 1] * a + bb;
        float s0 = y0 / (1.f + __expf(-y0));
        float s1 = y1 / (1.f + __expf(-y1));
        unsigned short h0 = f2bf(s0), l0 = f2bf(s0 - bf2f(h0));
        unsigned short h1 = f2bf(s1), l1 = f2bf(s1 - bf2f(h1));
        oh[j] = h0 | ((unsigned)h1 << 16);
        ol[j] = l0 | ((unsigned)l1 << 16);
    }
    ((uint4*)hi)[idx] = make_uint4(oh[0], oh[1], oh[2], oh[3]);
    ((uint4*)lo)[idx] = make_uint4(ol[0], ol[1], ol[2], ol[3]);
}

// GN + affine + SiLU on fp32 k -> TRANSPOSED bf16 hi/lo [B][M][C] (B-frag layout).
__global__ __launch_bounds__(256) void gn_silu_split_kT(
    const float* __restrict__ kf, unsigned short* __restrict__ th,
    unsigned short* __restrict__ tl, const float* __restrict__ stats,
    const float* __restrict__ scale, const float* __restrict__ bias)
{
    int bm = blockIdx.x;              // 8 batches * 128 m8-groups
    int b = bm >> 7, m8 = (bm & 127) * 8;
    int c = threadIdx.x;
    int gg = b * 32 + (c >> 3);
    float mean = stats[gg * 2], rstd = stats[gg * 2 + 1];
    float a  = scale[c] * rstd;
    float bb = bias[c] - mean * a;
    const float* src = kf + (((size_t)(b * 256 + c)) << 10) + m8;
    float4 f0 = *(const float4*)src;
    float4 f1 = *(const float4*)(src + 4);
    float xs[8] = {f0.x, f0.y, f0.z, f0.w, f1.x, f1.y, f1.z, f1.w};
    #pragma unroll
    for (int j = 0; j < 8; ++j) {
        float y = xs[j] * a + bb;
        float s = y / (1.f + __expf(-y));
        unsigned short h = f2bf(s), l = f2bf(s - bf2f(h));
        size_t o = ((size_t)b * M_ + m8 + j) * C_ + c;
        th[o] = h;
        tl[o] = l;
    }
}

// ---------------------------------------------------------------------------
// Fused flash attention, split-bf16 MFMA (3-term fp32 emulation).
// Block: 1 batch x 64 q-rows (16/wave). m-tile 32. Frags direct from global
// (L2-resident via blockIdx&7 = batch -> XCD pin). P transposed via per-wave LDS.
__global__ __launch_bounds__(256, 2) void attn_mfma(
    const unsigned short* __restrict__ qh, const unsigned short* __restrict__ qlo,
    const unsigned short* __restrict__ kth, const unsigned short* __restrict__ ktl,
    const unsigned short* __restrict__ vh, const unsigned short* __restrict__ vlo,
    const float* __restrict__ gamma, float* __restrict__ out)
{
    __shared__ __align__(16) unsigned short pH[4][16][40];
    __shared__ __align__(16) unsigned short pL[4][16][40];
    __shared__ float alphaS[4][16];
    __shared__ float linvS[4][16];

    int blk = blockIdx.x;
    int bat = blk & 7;
    int nt  = blk >> 3;
    int t = threadIdx.x;
    int w = t >> 6;
    int lane = t & 63;
    int ll = lane & 15;
    int qd = lane >> 4;
    int n0 = nt * 64 + w * 16;

    // q A-frags (held in registers across the whole m-loop; one-time load)
    short8 aqh[8], aql[8];
    {
        const unsigned short* qb1 = qh  + (size_t)bat * C_ * N_ + n0 + ll;
        const unsigned short* qb2 = qlo + (size_t)bat * C_ * N_ + n0 + ll;
        #pragma unroll
        for (int ks = 0; ks < 8; ++ks) {
            #pragma unroll
            for (int j = 0; j < 8; ++j) {
                size_t off = (size_t)(ks * 32 + qd * 8 + j) * N_;
                aqh[ks][j] = (short)qb1[off];
                aql[ks][j] = (short)qb2[off];
            }
        }
    }

    f32x4 oacc[16];
    #pragma unroll
    for (int i = 0; i < 16; ++i) oacc[i] = (f32x4){0.f, 0.f, 0.f, 0.f};
    float mrun[4] = {-3e38f, -3e38f, -3e38f, -3e38f};
    float lrun[4] = {0.f, 0.f, 0.f, 0.f};

    const unsigned short* ktbh = kth + (size_t)bat * M_ * C_ + (size_t)ll * C_ + qd * 8;
    const unsigned short* ktbl = ktl + (size_t)bat * M_ * C_ + (size_t)ll * C_ + qd * 8;
    const unsigned short* vbh  = vh  + (size_t)bat * C_ * M_ + (size_t)ll * M_ + qd * 8;
    const unsigned short* vbl  = vlo + (size_t)bat * C_ * M_ + (size_t)ll * M_ + qd * 8;

    for (int mt = 0; mt < 32; ++mt) {
        int m0 = mt * 32;
        f32x4 s0 = {0.f, 0.f, 0.f, 0.f}, s1 = {0.f, 0.f, 0.f, 0.f};
        const unsigned short* k0h = ktbh + (size_t)m0 * C_;
        const unsigned short* k0l = ktbl + (size_t)m0 * C_;
        const unsigned short* k1h = k0h + 16 * C_;
        const unsigned short* k1l = k0l + 16 * C_;
        #pragma unroll
        for (int ks = 0; ks < 8; ++ks) {
            short8 b0h = *(const short8*)(k0h + ks * 32);
            short8 b0l = *(const short8*)(k0l + ks * 32);
            short8 b1h = *(const short8*)(k1h + ks * 32);
            short8 b1l = *(const short8*)(k1l + ks * 32);
            s0 = __builtin_amdgcn_mfma_f32_16x16x32_bf16(aqh[ks], b0h, s0, 0, 0, 0);
            s1 = __builtin_amdgcn_mfma_f32_16x16x32_bf16(aqh[ks], b1h, s1, 0, 0, 0);
            s0 = __builtin_amdgcn_mfma_f32_16x16x32_bf16(aql[ks], b0h, s0, 0, 0, 0);
            s1 = __builtin_amdgcn_mfma_f32_16x16x32_bf16(aql[ks], b1h, s1, 0, 0, 0);
            s0 = __builtin_amdgcn_mfma_f32_16x16x32_bf16(aqh[ks], b0l, s0, 0, 0, 0);
            s1 = __builtin_amdgcn_mfma_f32_16x16x32_bf16(aqh[ks], b1l, s1, 0, 0, 0);
        }
        // online softmax on D-layout scores: lane holds rows qd*4+r, col ll (+16)
        float alpha4[4];
        #pragma unroll
        for (int r = 0; r < 4; ++r) {
            float mx = fmaxf(s0[r], s1[r]);
            mx = fmaxf(mx, __shfl_xor(mx, 1));
            mx = fmaxf(mx, __shfl_xor(mx, 2));
            mx = fmaxf(mx, __shfl_xor(mx, 4));
            mx = fmaxf(mx, __shfl_xor(mx, 8));
            float mn = fmaxf(mrun[r], mx);
            float al = __expf(mrun[r] - mn);
            mrun[r] = mn;
            float p0 = __expf(s0[r] - mn);
            float p1 = __expf(s1[r] - mn);
            float ps = p0 + p1;
            ps += __shfl_xor(ps, 1);
            ps += __shfl_xor(ps, 2);
            ps += __shfl_xor(ps, 4);
            ps += __shfl_xor(ps, 8);
            lrun[r] = lrun[r] * al + ps;
            alpha4[r] = al;
            unsigned short h0 = f2bf(p0), l0 = f2bf(p0 - bf2f(h0));
            unsigned short h1 = f2bf(p1), l1 = f2bf(p1 - bf2f(h1));
            int rn = qd * 4 + r;
            pH[w][rn][ll] = h0;  pH[w][rn][16 + ll] = h1;
            pL[w][rn][ll] = l0;  pL[w][rn][16 + ll] = l1;
        }
        if (ll == 0) {
            #pragma unroll
            for (int r = 0; r < 4; ++r) alphaS[w][qd * 4 + r] = alpha4[r];
        }
        __builtin_amdgcn_wave_barrier();   // intra-wave LDS RAW: compiler orders via lgkmcnt
        short8 bph = *(const short8*)&pH[w][ll][qd * 8];
        short8 bpl = *(const short8*)&pL[w][ll][qd * 8];
        float an = alphaS[w][ll];
        const unsigned short* vp0 = vbh + m0;
        const unsigned short* vp1 = vbl + m0;
        #pragma unroll
        for (int ct = 0; ct < 16; ++ct) {
            short8 avh = *(const short8*)(vp0 + (size_t)ct * 16 * M_);
            short8 avl = *(const short8*)(vp1 + (size_t)ct * 16 * M_);
            f32x4 o = oacc[ct];
            o[0] *= an; o[1] *= an; o[2] *= an; o[3] *= an;
            o = __builtin_amdgcn_mfma_f32_16x16x32_bf16(avh, bph, o, 0, 0, 0);
            o = __builtin_amdgcn_mfma_f32_16x16x32_bf16(avl, bph, o, 0, 0, 0);
            o = __builtin_amdgcn_mfma_f32_16x16x32_bf16(avh, bpl, o, 0, 0, 0);
            oacc[ct] = o;
        }
        __builtin_amdgcn_wave_barrier();   // WAR: reads before next iter's writes
    }
    if (ll == 0) {
        #pragma unroll
        for (int r = 0; r < 4; ++r) linvS[w][qd * 4 + r] = 1.f / lrun[r];
    }
    __builtin_amdgcn_wave_barrier();
    float li = linvS[w][ll] * gamma[0];
    float* ob = out + (size_t)bat * C_ * N_ + n0 + ll;
    #pragma unroll
    for (int ct = 0; ct < 16; ++ct) {
        #pragma unroll
        for (int r = 0; r < 4; ++r) {
            int c = ct * 16 + qd * 4 + r;
            ob[(size_t)c * N_] = oacc[ct][r] * li;
        }
    }
}

// ---------------------------------------------------------------------------
extern "C" void kernel_launch(void* const* d_in, const int* in_sizes, int n_in,
                              void* d_out, int out_size, void* d_ws, size_t ws_size,
                              hipStream_t stream)
{
    const float* x   = (const float*)d_in[0];
    const float* y   = (const float*)d_in[1];
    const float* Wq  = (const float*)d_in[2];
    const float* bq  = (const float*)d_in[3];
    const float* gqs = (const float*)d_in[4];
    const float* gqb = (const float*)d_in[5];
    const float* Wk  = (const float*)d_in[6];
    const float* bk  = (const float*)d_in[7];
    const float* gks = (const float*)d_in[8];
    const float* gkb = (const float*)d_in[9];
    const float* Wv  = (const float*)d_in[10];
    const float* bv  = (const float*)d_in[11];
    const float* gvs = (const float*)d_in[12];
    const float* gvb = (const float*)d_in[13];
    const float* gamma = (const float*)d_in[14];
    float* out = (float*)d_out;

    // ws layout (~67.2 MB): qH|qL bf16 33.6MB, k/v fp32 16.8MB, kT/v splits 16.8MB, stats
    char* base = (char*)d_ws;
    unsigned short* qH = (unsigned short*)base;
    unsigned short* qL = qH + 8388608;
    float* kf = (float*)(qL + 8388608);
    float* vf = kf + 2097152;
    unsigned short* kTh = (unsigned short*)(vf + 2097152);
    unsigned short* kTl = kTh + 2097152;
    unsigned short* vH  = kTl + 2097152;
    unsigned short* vL  = vH + 2097152;
    float* stq = (float*)(vL + 2097152);
    float* stk = stq + 512;
    float* stv = stk + 512;

    conv3x3_kernel<<<512, 256, 0, stream>>>(x, Wq, bq, qH, qL);
    conv2x2_kernel<<<256, 256, 0, stream>>>(y, Wk, bk, Wv, bv, kf, vf);
    gn_stats_pair<<<256, 256, 0, stream>>>(qH, qL, stq, 4096);
    gn_stats_kernel<<<256, 256, 0, stream>>>(kf, stk, 1024);
    gn_stats_kernel<<<256, 256, 0, stream>>>(vf, stv, 1024);
    gn_silu_pair<<<4096, 256, 0, stream>>>(qH, qL, stq, gqs, gqb, 0.0625f, 1048576);
    gn_silu_split_v<<<1024, 256, 0, stream>>>(vf, vH, vL, stv, gvs, gvb, 262144);
    gn_silu_split_kT<<<1024, 256, 0, stream>>>(kf, kTh, kTl, stk, gks, gkb);
    attn_mfma<<<512, 256, 0, stream>>>(qH, qL, kTh, kTl, vH, vL, gamma, out);
}